// Round 4
// baseline (5830.788 us; speedup 1.0000x reference)
//
#include <hip/hip_runtime.h>

#define B_SZ 512
#define T_ENC 140
#define E_DIM 256
#define H_DIM 512
#define O_DIM 64
#define PRED 140
#define T_TOT 280
#define NBLK 256

typedef short bf16x8 __attribute__((ext_vector_type(8)));
typedef float f32x4 __attribute__((ext_vector_type(4)));
typedef unsigned u32x4 __attribute__((ext_vector_type(4)));

static __device__ __forceinline__ unsigned short f2b(float x){
  union { float f; unsigned u; } v; v.f = x;
  unsigned r = v.u + 0x7fffu + ((v.u >> 16) & 1u);
  return (unsigned short)(r >> 16);
}
static __device__ __forceinline__ float sigmoidf_(float x){
  return 1.0f / (1.0f + __expf(-x));
}
static __device__ __forceinline__ float tanhf_(float x){
  float e2 = __expf(-2.0f * fabsf(x));
  float t = (1.0f - e2) / (1.0f + e2);
  return x < 0.0f ? -t : t;
}

// ---- device-coherent (L3) access: bypass L1/L2 so no fence/invalidate is ever needed ----
static __device__ __forceinline__ void st_wt_u16(unsigned short* p, unsigned v){
  asm volatile("global_store_short %0, %1, off sc0 sc1" :: "v"(p), "v"(v) : "memory");
}
static __device__ __forceinline__ void st_wt_f32(float* p, float v){
  asm volatile("global_store_dword %0, %1, off sc0 sc1" :: "v"(p), "v"(v) : "memory");
}
static __device__ __forceinline__ void st_wt_u32(unsigned* p, unsigned v){
  asm volatile("global_store_dword %0, %1, off sc0 sc1" :: "v"(p), "v"(v) : "memory");
}
static __device__ __forceinline__ bf16x8 ld_bp(const unsigned short* p){
  f32x4 r;
  asm volatile("global_load_dwordx4 %0, %1, off sc0 sc1" : "=v"(r) : "v"(p));
  union { f32x4 f; bf16x8 b; } u; u.f = r; return u.b;
}
static __device__ __forceinline__ float ld_bp_f32(const float* p){
  float r;
  asm volatile("global_load_dword %0, %1, off sc0 sc1" : "=v"(r) : "v"(p));
  return r;
}
static __device__ __forceinline__ void wait_vm0(){
  asm volatile("s_waitcnt vmcnt(0)" ::: "memory");
  __builtin_amdgcn_sched_barrier(0);
}
// poll load: embed the waitcnt (compiler doesn't track asm vmcnt)
static __device__ __forceinline__ u32x4 ld_poll4(const unsigned* p){
  u32x4 r;
  asm volatile("global_load_dwordx4 %0, %1, off sc0 sc1\n\ts_waitcnt vmcnt(0)"
               : "=v"(r) : "v"(p) : "memory");
  return r;
}

__global__ void k_cast(const float* __restrict__ src, unsigned short* __restrict__ dst, int n){
  int i = blockIdx.x * 256 + threadIdx.x;
  if (i < n) dst[i] = f2b(src[i]);
}

// out_W (E x H) -> outWT16 (H x E) bf16
__global__ void k_transpose_cast(const float* __restrict__ src, unsigned short* __restrict__ dst){
  int i = blockIdx.x * 256 + threadIdx.x;   // over H*E = 131072
  int j = i >> 8;
  int k = i & 255;
  dst[i] = f2b(src[k * H_DIM + j]);
}

__global__ void k_init_h(const float* __restrict__ eh, float* __restrict__ h, unsigned short* __restrict__ h16){
  int i = blockIdx.x * 256 + threadIdx.x;   // B*H
  float v = eh[i];
  h[i] = v; h16[i] = f2b(v);
}

__global__ void k_x0(const float* __restrict__ enc, unsigned short* __restrict__ x016){
  int i = blockIdx.x * 256 + threadIdx.x;   // B*E
  int b = i >> 8; int k = i & 255;
  x016[i] = f2b(enc[((size_t)b * T_ENC + (T_ENC - 1)) * E_DIM + k]);
}

// barrier slot arrays: slotsB[256]=0; slotsA[0..65]=0, [66..255]=0x7FFFFFFF (pad = always-passed)
__global__ void k_barinit(unsigned* slotsB, unsigned* slotsA){
  int i = threadIdx.x;
  slotsB[i] = 0u;
  slotsA[i] = (i < 66) ? 0u : 0x7FFFFFFFu;
}

// bias_big = [emb_b + emb_W@out_b (512) | b_hh (1536) | reg_b + reg_W@out_b (64)]
__global__ void k_bias(const float* __restrict__ embW, const float* __restrict__ emb_b,
                       const float* __restrict__ out_b, const float* __restrict__ b_hh,
                       const float* __restrict__ regW, const float* __restrict__ reg_b,
                       float* __restrict__ bias_big){
  int i = blockIdx.x * 256 + threadIdx.x;
  if (i < 512){
    float s = emb_b[i];
    for (int k = 0; k < 256; k++) s += embW[i * 256 + k] * out_b[k];
    bias_big[i] = s;
  } else if (i < 2048){
    bias_big[i] = b_hh[i - 512];
  } else if (i < 2112){
    int o = i - 2048;
    float s = reg_b[o];
    for (int k = 0; k < 256; k++) s += regW[o * 256 + k] * out_b[k];
    bias_big[i] = s;
  }
}

// Generic C = A @ W^T (+bias). A: M x K (bf16 or f32), W: N x K bf16 row-major.
// mode 0: f32 out (ldc); 1: bf16 out; 2: relu + bf16 out; 3: f32 out with encoder (b,t) row remap
__global__ __launch_bounds__(256)
void k_gemm(const void* __restrict__ Aptr, int a_is_f32,
            const unsigned short* __restrict__ W,
            const float* __restrict__ bias,
            void* __restrict__ Cptr, int mode,
            int M, int N, int K, int ldc)
{
  const int lane = threadIdx.x & 63;
  const int wave = threadIdx.x >> 6;
  const int ln = lane & 15;
  const int kq = lane >> 4;
  const int m0 = blockIdx.y * 64 + wave * 16;
  const int n0 = blockIdx.x * 64;

  f32x4 acc[4] = {};
  const int arow = m0 + ln;
  const unsigned short* wp = W + (size_t)(n0 + ln) * K + kq * 8;
  const int nk = K >> 5;

  if (a_is_f32){
    const float* ap = (const float*)Aptr + (size_t)arow * K + kq * 8;
    for (int t = 0; t < nk; ++t){
      f32x4 u0 = *(const f32x4*)(ap);
      f32x4 u1 = *(const f32x4*)(ap + 4);
      bf16x8 af;
      af[0] = (short)f2b(u0[0]); af[1] = (short)f2b(u0[1]);
      af[2] = (short)f2b(u0[2]); af[3] = (short)f2b(u0[3]);
      af[4] = (short)f2b(u1[0]); af[5] = (short)f2b(u1[1]);
      af[6] = (short)f2b(u1[2]); af[7] = (short)f2b(u1[3]);
      #pragma unroll
      for (int j = 0; j < 4; j++){
        bf16x8 wf = *(const bf16x8*)(wp + (size_t)(16 * j) * K);
        acc[j] = __builtin_amdgcn_mfma_f32_16x16x32_bf16(af, wf, acc[j], 0, 0, 0);
      }
      ap += 32; wp += 32;
    }
  } else {
    const unsigned short* ap = (const unsigned short*)Aptr + (size_t)arow * K + kq * 8;
    for (int t = 0; t < nk; ++t){
      bf16x8 af = *(const bf16x8*)ap;
      #pragma unroll
      for (int j = 0; j < 4; j++){
        bf16x8 wf = *(const bf16x8*)(wp + (size_t)(16 * j) * K);
        acc[j] = __builtin_amdgcn_mfma_f32_16x16x32_bf16(af, wf, acc[j], 0, 0, 0);
      }
      ap += 32; wp += 32;
    }
  }

  #pragma unroll
  for (int j = 0; j < 4; j++){
    int col = n0 + 16 * j + ln;
    float bv = bias ? bias[col] : 0.0f;
    #pragma unroll
    for (int r = 0; r < 4; r++){
      int orow = m0 + kq * 4 + r;
      float v = acc[j][r] + bv;
      if (mode == 0){
        ((float*)Cptr)[(size_t)orow * ldc + col] = v;
      } else if (mode == 1){
        ((unsigned short*)Cptr)[(size_t)orow * ldc + col] = f2b(v);
      } else if (mode == 2){
        ((unsigned short*)Cptr)[(size_t)orow * ldc + col] = f2b(v > 0.f ? v : 0.f);
      } else {
        int bb = orow / T_ENC;
        int tt = orow - bb * T_ENC;
        ((float*)Cptr)[((size_t)bb * T_TOT + tt) * O_DIM + col] = v;
      }
    }
  }
}

// ---------------- persistent GRU loop (flat single-hop barrier, no sleeps) ----------------

// wave 0 polls 256 slots with ONE dwordx4 per lane; no aggregator, no fan-out.
static __device__ __forceinline__ void poll_all(const unsigned* base, unsigned gen, int tid){
  const unsigned* p = base + tid * 4;
  for (;;){
    u32x4 v = ld_poll4(p);
    int ok = (v[0] >= gen) & (v[1] >= gen) & (v[2] >= gen) & (v[3] >= gen);
    if (__all(ok)) break;
  }
}

static __device__ __forceinline__ void emitA(unsigned short* __restrict__ e16,
                                             float* __restrict__ gh,
                                             float* __restrict__ out,
                                             int b, int colA, float v, int s){
  if (colA < 512){
    st_wt_u16(e16 + (size_t)b * H_DIM + colA, (unsigned)f2b(v > 0.f ? v : 0.f));
  } else if (colA < 2048){
    st_wt_f32(gh + (size_t)b * 1536 + (colA - 512), v);
  } else {
    out[((size_t)b * T_TOT + T_ENC + s) * O_DIM + (colA - 2048)] = v;   // normal store, never re-read
  }
}

// One block per CU. LDS: A-slice 64KB (64 cols of Wbig, blocks 0..65) + B-slice 48KB (48 gate-cols of w_ih).
// Phase A: 33 supertiles (64 cols) x 2 m-halves = 66 blocks. Phase B: 32 j-tiles x 8 m-slices = 256 blocks.
__global__ __launch_bounds__(512, 2)
void k_persist(const unsigned short* __restrict__ Wbig,
               const unsigned short* __restrict__ wih16,
               const float* __restrict__ bias_big,
               const float* __restrict__ b_ih,
               unsigned short* __restrict__ e16,
               float* __restrict__ gh,
               float* __restrict__ h,
               unsigned short* __restrict__ h16,
               float* __restrict__ out,
               unsigned* __restrict__ slotsB,
               unsigned* __restrict__ slotsA)
{
  __shared__ short lds_s[57344];          // 112 KiB: [0,32768) A (64KB), [32768,57344) B (48KB)
  short* wA = lds_s;
  short* wB = lds_s + 32768;

  const int g    = blockIdx.x;
  const int tid  = threadIdx.x;
  const int wv   = tid >> 6;
  const int lane = tid & 63;
  const int ln   = lane & 15;
  const int kq   = lane >> 4;

  const int at2 = g >> 1;          // supertile (64 cols), valid for g < 66
  const int jt  = g & 31;
  const int mtB = g >> 5;

  // ---- stage weights into LDS (once), k-major 16B granules ----
  if (g < 66){
    // A: granule (kk, c in 0..63) -> phys (kk>>2)*256 + c*4 + (kk&3); per-(t,jn) read is contiguous 1KB
    for (int q = tid; q < 4096; q += 512){
      int kk = q & 63, c = q >> 6;
      bf16x8 v = *(const bf16x8*)(Wbig + (size_t)(at2 * 64 + c) * H_DIM + kk * 8);
      int p = ((kk >> 2) << 8) + (c << 2) + (kk & 3);
      *(bf16x8*)(wA + p * 8) = v;
    }
  }
  // B: 48 cols = gate*16 + ln; granule (kk,c) -> phys (kk>>2)*192 + c*4 + (kk&3)
  for (int q = tid; q < 3072; q += 512){
    int kk = q & 63, c = q >> 6;
    int row = ((c >> 4) << 9) + jt * 16 + (c & 15);
    bf16x8 v = *(const bf16x8*)(wih16 + (size_t)row * H_DIM + kk * 8);
    int p = (kk >> 2) * 192 + (c << 2) + (kk & 3);
    *(bf16x8*)(wB + p * 8) = v;
  }
  __syncthreads();

  // hoisted per-thread constants
  const int jcol = jt * 16 + ln;
  const float bR = b_ih[jcol], bZ = b_ih[512 + jcol], bN = b_ih[1024 + jcol];
  float bvA[4];
  #pragma unroll
  for (int jn = 0; jn < 4; ++jn)
    bvA[jn] = bias_big[(g < 66) ? (at2 * 64 + jn * 16 + ln) : 0];

  for (int s = 0; s < PRED; ++s){
    const unsigned gen = (unsigned)(s + 1);

    // ---- phase B: gi = e16 @ w_ih^T slice, GRU gating -> h, h16 ----
    if (wv < 4){
      const int m0 = mtB * 64 + wv * 16;
      const unsigned short* ap = e16 + (size_t)(m0 + ln) * H_DIM + kq * 8;
      bf16x8 af[16];
      #pragma unroll
      for (int t = 0; t < 16; ++t) af[t] = ld_bp(ap + t * 32);
      float gR[4], gZ[4], gN[4];
      #pragma unroll
      for (int r = 0; r < 4; ++r){
        const float* ghrow = gh + (size_t)(m0 + kq * 4 + r) * 1536;
        gR[r] = ld_bp_f32(ghrow + jcol);
        gZ[r] = ld_bp_f32(ghrow + 512 + jcol);
        gN[r] = ld_bp_f32(ghrow + 1024 + jcol);
      }
      wait_vm0();
      f32x4 aR = {}, aZ = {}, aN = {};
      const short* lb = wB + (ln * 4 + kq) * 8;
      #pragma unroll
      for (int t = 0; t < 16; ++t){
        aR = __builtin_amdgcn_mfma_f32_16x16x32_bf16(af[t], *(const bf16x8*)(lb + (t * 192      ) * 8), aR, 0, 0, 0);
        aZ = __builtin_amdgcn_mfma_f32_16x16x32_bf16(af[t], *(const bf16x8*)(lb + (t * 192 +  64) * 8), aZ, 0, 0, 0);
        aN = __builtin_amdgcn_mfma_f32_16x16x32_bf16(af[t], *(const bf16x8*)(lb + (t * 192 + 128) * 8), aN, 0, 0, 0);
      }
      #pragma unroll
      for (int r = 0; r < 4; ++r){
        int b = m0 + kq * 4 + r;
        float rg = sigmoidf_(aR[r] + bR + gR[r]);
        float z  = sigmoidf_(aZ[r] + bZ + gZ[r]);
        float nn = tanhf_(aN[r] + bN + rg * gN[r]);
        float hv = (1.f - z) * nn + z * h[(size_t)b * H_DIM + jcol];   // h is block-private: normal cache OK
        h[(size_t)b * H_DIM + jcol] = hv;
        st_wt_u16(h16 + (size_t)b * H_DIM + jcol, (unsigned)f2b(hv));
      }
    }

    // ---- arrive B; A-blocks wait for all B, do phase A, arrive A; others wait on A directly ----
    asm volatile("s_waitcnt vmcnt(0)" ::: "memory");   // drain this wave's WT stores
    __syncthreads();                                   // => whole block drained

    if (g < 66){
      if (tid < 64){
        if (tid == 0) st_wt_u32(slotsB + g, gen);
        poll_all(slotsB, gen, tid);
      }
      __syncthreads();

      // ---- phase A: T = h16 @ Wbig^T supertile (64 cols x half-M), single load batch ----
      if (s < PRED - 1 || at2 == 32){
        const int mbase = (g & 1) * 256 + wv * 32;
        const unsigned short* r0 = h16 + (size_t)(mbase + ln) * H_DIM + kq * 8;
        const unsigned short* r1 = r0 + (size_t)16 * H_DIM;
        bf16x8 a0[16], a1[16];
        #pragma unroll
        for (int t = 0; t < 16; ++t){
          a0[t] = ld_bp(r0 + t * 32);
          a1[t] = ld_bp(r1 + t * 32);
        }
        wait_vm0();
        f32x4 acc0[4] = {}, acc1[4] = {};
        #pragma unroll
        for (int t = 0; t < 16; ++t){
          #pragma unroll
          for (int jn = 0; jn < 4; ++jn){
            bf16x8 w = *(const bf16x8*)(wA + (t * 256 + (jn * 16 + ln) * 4 + kq) * 8);
            acc0[jn] = __builtin_amdgcn_mfma_f32_16x16x32_bf16(a0[t], w, acc0[jn], 0, 0, 0);
            acc1[jn] = __builtin_amdgcn_mfma_f32_16x16x32_bf16(a1[t], w, acc1[jn], 0, 0, 0);
          }
        }
        #pragma unroll
        for (int jn = 0; jn < 4; ++jn){
          int col = at2 * 64 + jn * 16 + ln;
          #pragma unroll
          for (int r = 0; r < 4; ++r){
            emitA(e16, gh, out, mbase + kq * 4 + r,      col, acc0[jn][r] + bvA[jn], s);
            emitA(e16, gh, out, mbase + 16 + kq * 4 + r, col, acc1[jn][r] + bvA[jn], s);
          }
        }
      }
      asm volatile("s_waitcnt vmcnt(0)" ::: "memory");
      __syncthreads();
      if (tid < 64){
        if (tid == 0) st_wt_u32(slotsA + g, gen);
        poll_all(slotsA, gen, tid);
      }
      __syncthreads();
    } else {
      // idle in A: signal B arrival, then wait directly for all A producers (pad slots always pass)
      if (tid < 64){
        if (tid == 0) st_wt_u32(slotsB + g, gen);
        poll_all(slotsA, gen, tid);
      }
      __syncthreads();
    }
  }
}

extern "C" void kernel_launch(void* const* d_in, const int* in_sizes, int n_in,
                              void* d_out, int out_size, void* d_ws, size_t ws_size,
                              hipStream_t stream)
{
  const float* enc   = (const float*)d_in[0];
  const float* ehid  = (const float*)d_in[1];
  const float* embW  = (const float*)d_in[2];
  const float* emb_b = (const float*)d_in[3];
  const float* w_ih  = (const float*)d_in[4];
  const float* w_hh  = (const float*)d_in[5];
  const float* b_ih  = (const float*)d_in[6];
  const float* b_hh  = (const float*)d_in[7];
  const float* out_W = (const float*)d_in[8];
  const float* out_b = (const float*)d_in[9];
  const float* reg_W = (const float*)d_in[10];
  const float* reg_b = (const float*)d_in[11];
  float* out = (float*)d_out;

  char* ws = (char*)d_ws;
  size_t off = 0;
  auto alloc = [&](size_t bytes)->char*{
    char* p = ws + off; off += (bytes + 255) & ~(size_t)255; return p;
  };
  unsigned short* Wbig    = (unsigned short*)alloc((size_t)2112 * 512 * 2);
  unsigned short* wih16   = (unsigned short*)alloc((size_t)1536 * 512 * 2);
  unsigned short* embW16  = (unsigned short*)alloc((size_t)512 * 256 * 2);
  unsigned short* regW16  = (unsigned short*)alloc((size_t)64 * 256 * 2);
  unsigned short* outWT16 = (unsigned short*)alloc((size_t)512 * 256 * 2);
  float*          bias_big= (float*)alloc((size_t)2112 * 4);
  unsigned short* e16     = (unsigned short*)alloc((size_t)512 * 512 * 2);
  float*          gh      = (float*)alloc((size_t)512 * 1536 * 4);
  float*          h       = (float*)alloc((size_t)512 * 512 * 4);
  unsigned short* h16     = (unsigned short*)alloc((size_t)512 * 512 * 2);
  unsigned short* x016    = (unsigned short*)alloc((size_t)512 * 256 * 2);
  unsigned*       slotsB  = (unsigned*)alloc(1024);
  unsigned*       slotsA  = (unsigned*)alloc(1024);

  // ---- precompute (runs every call; ws is re-poisoned) ----
  k_barinit<<<1, 256, 0, stream>>>(slotsB, slotsA);
  k_cast<<<(1536 * 512) / 256, 256, 0, stream>>>(w_ih, wih16, 1536 * 512);
  k_cast<<<(1536 * 512) / 256, 256, 0, stream>>>(w_hh, Wbig + (size_t)512 * 512, 1536 * 512);
  k_cast<<<(512 * 256) / 256, 256, 0, stream>>>(embW, embW16, 512 * 256);
  k_cast<<<(64 * 256) / 256, 256, 0, stream>>>(reg_W, regW16, 64 * 256);
  k_transpose_cast<<<512, 256, 0, stream>>>(out_W, outWT16);
  k_bias<<<9, 256, 0, stream>>>(embW, emb_b, out_b, b_hh, reg_W, reg_b, bias_big);
  k_init_h<<<(512 * 512) / 256, 256, 0, stream>>>(ehid, h, h16);
  k_x0<<<(512 * 256) / 256, 256, 0, stream>>>(enc, x016);

  // W_comb = emb_W @ out_W  -> Wbig rows [0,512)
  k_gemm<<<dim3(8, 8), 256, 0, stream>>>(embW, 1, outWT16, nullptr, Wbig, 1, 512, 512, 256, 512);
  // W_or = reg_W @ out_W  -> Wbig rows [2048,2112)
  k_gemm<<<dim3(8, 1), 256, 0, stream>>>(reg_W, 1, outWT16, nullptr, Wbig + (size_t)2048 * 512, 1, 64, 512, 256, 512);
  // e0 = relu(x0 @ emb_W^T + emb_b)
  k_gemm<<<dim3(8, 8), 256, 0, stream>>>(x016, 0, embW16, emb_b, e16, 2, 512, 512, 256, 512);
  // gh0 = h0 @ w_hh^T + b_hh
  k_gemm<<<dim3(24, 8), 256, 0, stream>>>(h16, 0, Wbig + (size_t)512 * 512, b_hh, gh, 0, 512, 1536, 512, 1536);
  // encoder projection: out[:, 0:140, :] = enc @ reg_W^T + reg_b
  k_gemm<<<dim3(1, 1120), 256, 0, stream>>>(enc, 1, regW16, reg_b, out, 3, 71680, 64, 256, 0);

  // ---- 140 GRU steps in ONE persistent kernel (flat single-hop barriers) ----
  k_persist<<<dim3(NBLK), dim3(512), 0, stream>>>(Wbig, wih16, bias_big, b_ih,
                                                  e16, gh, h, h16, out, slotsB, slotsA);
}

// Round 6
// 3688.571 us; speedup vs baseline: 1.5808x; 1.5808x over previous
//
#include <hip/hip_runtime.h>

#define B_SZ 512
#define T_ENC 140
#define E_DIM 256
#define H_DIM 512
#define O_DIM 64
#define PRED 140
#define T_TOT 280
#define NBLK 256

typedef short bf16x8 __attribute__((ext_vector_type(8)));
typedef float f32x4 __attribute__((ext_vector_type(4)));
typedef unsigned u32x4 __attribute__((ext_vector_type(4)));

static __device__ __forceinline__ unsigned short f2b(float x){
  union { float f; unsigned u; } v; v.f = x;
  unsigned r = v.u + 0x7fffu + ((v.u >> 16) & 1u);
  return (unsigned short)(r >> 16);
}
static __device__ __forceinline__ float sigmoidf_(float x){
  return 1.0f / (1.0f + __expf(-x));
}
static __device__ __forceinline__ float tanhf_(float x){
  float e2 = __expf(-2.0f * fabsf(x));
  float t = (1.0f - e2) / (1.0f + e2);
  return x < 0.0f ? -t : t;
}

// invalidate this CU's vector L1 (cheap, 32KB). Makes plain/sc0 loads read the local L2.
static __device__ __forceinline__ void binv(){ asm volatile("buffer_inv" ::: "memory"); }

// ---- transports. FAST: same-XCD via local L2 (plain/sc0 stores, binv+sc0 loads).
// ---- SLOW: device-coherent via MALL (sc0 sc1 both ways) — proven in rounds 2-4.
template<bool FAST>
static __device__ __forceinline__ bf16x8 ldx4a(const unsigned short* p){
  f32x4 r;
  if constexpr (FAST) asm volatile("global_load_dwordx4 %0, %1, off sc0" : "=v"(r) : "v"(p));
  else                asm volatile("global_load_dwordx4 %0, %1, off sc0 sc1" : "=v"(r) : "v"(p));
  union { f32x4 f; bf16x8 b; } u; u.f = r; return u.b;
}
template<bool FAST>
static __device__ __forceinline__ float ld1(const float* p){
  float r;
  if constexpr (FAST) asm volatile("global_load_dword %0, %1, off sc0" : "=v"(r) : "v"(p));
  else                asm volatile("global_load_dword %0, %1, off sc0 sc1" : "=v"(r) : "v"(p));
  return r;
}
template<bool FAST>
static __device__ __forceinline__ void st16(unsigned short* p, unsigned v){
  if constexpr (FAST) asm volatile("global_store_short %0, %1, off" :: "v"(p), "v"(v) : "memory");
  else                asm volatile("global_store_short %0, %1, off sc0 sc1" :: "v"(p), "v"(v) : "memory");
}
template<bool FAST>
static __device__ __forceinline__ void st32f(float* p, float v){
  if constexpr (FAST) asm volatile("global_store_dword %0, %1, off" :: "v"(p), "v"(v) : "memory");
  else                asm volatile("global_store_dword %0, %1, off sc0 sc1" :: "v"(p), "v"(v) : "memory");
}
static __device__ __forceinline__ void wait_vm0(){
  asm volatile("s_waitcnt vmcnt(0)" ::: "memory");
  __builtin_amdgcn_sched_barrier(0);
}
static __device__ __forceinline__ unsigned ld_mall(const unsigned* p){
  unsigned r;
  asm volatile("global_load_dword %0, %1, off sc0 sc1\n\ts_waitcnt vmcnt(0)" : "=v"(r) : "v"(p) : "memory");
  return r;
}
static __device__ __forceinline__ void st_mall(unsigned* p, unsigned v){
  asm volatile("global_store_dword %0, %1, off sc0 sc1\n\ts_waitcnt vmcnt(0)" :: "v"(p), "v"(v) : "memory");
}

__global__ void k_cast(const float* __restrict__ src, unsigned short* __restrict__ dst, int n){
  int i = blockIdx.x * 256 + threadIdx.x;
  if (i < n) dst[i] = f2b(src[i]);
}

__global__ void k_transpose_cast(const float* __restrict__ src, unsigned short* __restrict__ dst){
  int i = blockIdx.x * 256 + threadIdx.x;   // over H*E = 131072
  int j = i >> 8;
  int k = i & 255;
  dst[i] = f2b(src[k * H_DIM + j]);
}

__global__ void k_init_h(const float* __restrict__ eh, float* __restrict__ h, unsigned short* __restrict__ h16){
  int i = blockIdx.x * 256 + threadIdx.x;   // B*H
  float v = eh[i];
  h[i] = v; h16[i] = f2b(v);
}

__global__ void k_x0(const float* __restrict__ enc, unsigned short* __restrict__ x016){
  int i = blockIdx.x * 256 + threadIdx.x;   // B*E
  int b = i >> 8; int k = i & 255;
  x016[i] = f2b(enc[((size_t)b * T_ENC + (T_ENC - 1)) * E_DIM + k]);
}

// pristine copies for island-local restart
__global__ void k_dup(const unsigned short* __restrict__ e16, unsigned short* __restrict__ e0c,
                      const float* __restrict__ gh, float* __restrict__ ghc){
  int i = blockIdx.x * 256 + threadIdx.x;    // 262144 threads
  e0c[i] = e16[i];
  ghc[i] = gh[i];
  ghc[i + 262144] = gh[i + 262144];
  ghc[i + 524288] = gh[i + 524288];
}

// bias_big = [emb_b + emb_W@out_b (512) | b_hh (1536) | reg_b + reg_W@out_b (64)]
__global__ void k_bias(const float* __restrict__ embW, const float* __restrict__ emb_b,
                       const float* __restrict__ out_b, const float* __restrict__ b_hh,
                       const float* __restrict__ regW, const float* __restrict__ reg_b,
                       float* __restrict__ bias_big){
  int i = blockIdx.x * 256 + threadIdx.x;
  if (i < 512){
    float s = emb_b[i];
    for (int k = 0; k < 256; k++) s += embW[i * 256 + k] * out_b[k];
    bias_big[i] = s;
  } else if (i < 2048){
    bias_big[i] = b_hh[i - 512];
  } else if (i < 2112){
    int o = i - 2048;
    float s = reg_b[o];
    for (int k = 0; k < 256; k++) s += regW[o * 256 + k] * out_b[k];
    bias_big[i] = s;
  }
}

// Generic C = A @ W^T (+bias). A: M x K (bf16 or f32), W: N x K bf16 row-major.
__global__ __launch_bounds__(256)
void k_gemm(const void* __restrict__ Aptr, int a_is_f32,
            const unsigned short* __restrict__ W,
            const float* __restrict__ bias,
            void* __restrict__ Cptr, int mode,
            int M, int N, int K, int ldc)
{
  const int lane = threadIdx.x & 63;
  const int wave = threadIdx.x >> 6;
  const int ln = lane & 15;
  const int kq = lane >> 4;
  const int m0 = blockIdx.y * 64 + wave * 16;
  const int n0 = blockIdx.x * 64;

  f32x4 acc[4] = {};
  const int arow = m0 + ln;
  const unsigned short* wp = W + (size_t)(n0 + ln) * K + kq * 8;
  const int nk = K >> 5;

  if (a_is_f32){
    const float* ap = (const float*)Aptr + (size_t)arow * K + kq * 8;
    for (int t = 0; t < nk; ++t){
      f32x4 u0 = *(const f32x4*)(ap);
      f32x4 u1 = *(const f32x4*)(ap + 4);
      bf16x8 af;
      af[0] = (short)f2b(u0[0]); af[1] = (short)f2b(u0[1]);
      af[2] = (short)f2b(u0[2]); af[3] = (short)f2b(u0[3]);
      af[4] = (short)f2b(u1[0]); af[5] = (short)f2b(u1[1]);
      af[6] = (short)f2b(u1[2]); af[7] = (short)f2b(u1[3]);
      #pragma unroll
      for (int j = 0; j < 4; j++){
        bf16x8 wf = *(const bf16x8*)(wp + (size_t)(16 * j) * K);
        acc[j] = __builtin_amdgcn_mfma_f32_16x16x32_bf16(af, wf, acc[j], 0, 0, 0);
      }
      ap += 32; wp += 32;
    }
  } else {
    const unsigned short* ap = (const unsigned short*)Aptr + (size_t)arow * K + kq * 8;
    for (int t = 0; t < nk; ++t){
      bf16x8 af = *(const bf16x8*)ap;
      #pragma unroll
      for (int j = 0; j < 4; j++){
        bf16x8 wf = *(const bf16x8*)(wp + (size_t)(16 * j) * K);
        acc[j] = __builtin_amdgcn_mfma_f32_16x16x32_bf16(af, wf, acc[j], 0, 0, 0);
      }
      ap += 32; wp += 32;
    }
  }

  #pragma unroll
  for (int j = 0; j < 4; j++){
    int col = n0 + 16 * j + ln;
    float bv = bias ? bias[col] : 0.0f;
    #pragma unroll
    for (int r = 0; r < 4; r++){
      int orow = m0 + kq * 4 + r;
      float v = acc[j][r] + bv;
      if (mode == 0){
        ((float*)Cptr)[(size_t)orow * ldc + col] = v;
      } else if (mode == 1){
        ((unsigned short*)Cptr)[(size_t)orow * ldc + col] = f2b(v);
      } else if (mode == 2){
        ((unsigned short*)Cptr)[(size_t)orow * ldc + col] = f2b(v > 0.f ? v : 0.f);
      } else {
        int bb = orow / T_ENC;
        int tt = orow - bb * T_ENC;
        ((float*)Cptr)[((size_t)bb * T_TOT + tt) * O_DIM + col] = v;
      }
    }
  }
}

// ---------------- persistent GRU: 8 XCD-islands, watchdogged fast path + slow rerun ----------------

// SLOW island barrier (sc1 = truthful, cannot stale-hang). 32 slots/island, 64-lane poll.
static __device__ void gbar_slow(unsigned* slots, int rg, int sl, unsigned gen, int tid){
  asm volatile("s_waitcnt vmcnt(0)" ::: "memory");
  __syncthreads();
  if (tid < 64){
    unsigned* base = slots + rg * 64;
    if (tid == 0){
      asm volatile("global_store_dword %0, %1, off sc0 sc1" :: "v"(base + sl), "v"(gen) : "memory");
    }
    const unsigned* p = base + (tid & 31);
    for (;;){
      unsigned v;
      asm volatile("global_load_dword %0, %1, off sc0 sc1\n\ts_waitcnt vmcnt(0)" : "=v"(v) : "v"(p) : "memory");
      if (__all((int)(v >= gen))) break;
      __builtin_amdgcn_s_sleep(8);
    }
  }
  __syncthreads();
}

// FAST island barrier: local-L2 flags, binv per poll, watchdog -> abort (sc1).
static __device__ __forceinline__ bool gbar_fast(unsigned* slots, unsigned* abortf,
                                                 volatile unsigned* s_ab, int rg, int sl,
                                                 unsigned gen, int tid){
  asm volatile("s_waitcnt vmcnt(0)" ::: "memory");   // drain data stores to local L2
  __syncthreads();
  if (tid < 64){
    unsigned* base = slots + rg * 64;
    if (tid == 0){
      asm volatile("global_store_dword %0, %1, off sc0" :: "v"(base + sl), "v"(gen) : "memory");
    }
    const unsigned* p = base + (tid & 31);
    unsigned it = 0, ab = 0;
    for (;;){
      binv();
      unsigned v;
      asm volatile("global_load_dword %0, %1, off sc0\n\ts_waitcnt vmcnt(0)" : "=v"(v) : "v"(p) : "memory");
      if (__all((int)(v >= gen))) break;
      if ((++it & 2047u) == 0u){
        unsigned a = ld_mall(abortf + rg);
        if (a != 0u || it >= 16384u){
          if (a == 0u && tid == 0) st_mall(abortf + rg, 1u);
          ab = 1u; break;
        }
      }
    }
    if (tid == 0) *s_ab = ab;
  }
  __syncthreads();
  return *s_ab == 0u;
}

// unified step loop; FAST aborts return false.
template<bool FAST>
static __device__ bool run_loop(int rg, int sl, int t0, int nt,
    const short* wA, const short* wB,
    const float* __restrict__ bias_big, const float* __restrict__ b_ih,
    unsigned short* __restrict__ e16, float* __restrict__ gh,
    float* __restrict__ h, unsigned short* __restrict__ h16,
    float* __restrict__ out,
    unsigned* sB, unsigned* sA, unsigned* abortf, volatile unsigned* s_ab, int tid)
{
  const int wv = tid >> 6, lane = tid & 63, ln = lane & 15, kq = lane >> 4;
  const int jcol = sl * 16 + ln;
  const float bR = b_ih[jcol], bZ = b_ih[512 + jcol], bN = b_ih[1024 + jcol];
  const int mf = wv & 3, hh = wv >> 2;
  const int nA = (nt + 1) >> 1;
  const int tloc0 = hh ? nA : 0;
  const int tcnt = hh ? (nt - nA) : nA;      // 2 or 3
  const int am0 = rg * 64 + mf * 16;

  for (int s = 0; s < PRED; ++s){
    // ---- phase B: gi = e16 @ w_ih^T (48 gate-cols), GRU gating -> h, h16 ----
    if (wv < 4){
      if constexpr (FAST) binv();
      const int m0 = rg * 64 + wv * 16;
      const unsigned short* ap = e16 + (size_t)(m0 + ln) * H_DIM + kq * 8;
      bf16x8 af[16];
      #pragma unroll
      for (int t = 0; t < 16; ++t) af[t] = ldx4a<FAST>(ap + t * 32);
      float gR[4], gZ[4], gN[4];
      #pragma unroll
      for (int r = 0; r < 4; ++r){
        const float* ghrow = gh + (size_t)(m0 + kq * 4 + r) * 1536;
        gR[r] = ld1<FAST>(ghrow + jcol);
        gZ[r] = ld1<FAST>(ghrow + 512 + jcol);
        gN[r] = ld1<FAST>(ghrow + 1024 + jcol);
      }
      wait_vm0();
      f32x4 aR = {}, aZ = {}, aN = {};
      const short* lb = wB + (ln * 4 + kq) * 8;
      #pragma unroll
      for (int t = 0; t < 16; ++t){
        aR = __builtin_amdgcn_mfma_f32_16x16x32_bf16(af[t], *(const bf16x8*)(lb + (t * 192      ) * 8), aR, 0, 0, 0);
        aZ = __builtin_amdgcn_mfma_f32_16x16x32_bf16(af[t], *(const bf16x8*)(lb + (t * 192 +  64) * 8), aZ, 0, 0, 0);
        aN = __builtin_amdgcn_mfma_f32_16x16x32_bf16(af[t], *(const bf16x8*)(lb + (t * 192 + 128) * 8), aN, 0, 0, 0);
      }
      #pragma unroll
      for (int r = 0; r < 4; ++r){
        int b = m0 + kq * 4 + r;
        float rr = sigmoidf_(aR[r] + bR + gR[r]);
        float z  = sigmoidf_(aZ[r] + bZ + gZ[r]);
        float nn = tanhf_(aN[r] + bN + rr * gN[r]);
        float hv = (1.f - z) * nn + z * h[(size_t)b * H_DIM + jcol];   // h block-private
        h[(size_t)b * H_DIM + jcol] = hv;
        st16<FAST>(h16 + (size_t)b * H_DIM + jcol, (unsigned)f2b(hv));
      }
    }
    if constexpr (FAST){
      if (!gbar_fast(sB, abortf, s_ab, rg, sl, (unsigned)(s + 1), tid)) return false;
    } else {
      gbar_slow(sB, rg, sl, (unsigned)(s + 1), tid);
    }

    // ---- phase A: T = h16 @ Wbig^T (this block's col-tiles) -> e16 / gh / out ----
    if (s < PRED - 1 || sl == 31){
      if constexpr (FAST) binv();
      const unsigned short* rp = h16 + (size_t)(am0 + ln) * H_DIM + kq * 8;
      bf16x8 af[16];
      #pragma unroll
      for (int t = 0; t < 16; ++t) af[t] = ldx4a<FAST>(rp + t * 32);
      wait_vm0();
      f32x4 acc[3];
      #pragma unroll
      for (int ti = 0; ti < 3; ++ti) acc[ti] = (f32x4){0.f, 0.f, 0.f, 0.f};
      if (tcnt == 3){
        #pragma unroll
        for (int t = 0; t < 16; ++t){
          #pragma unroll
          for (int ti = 0; ti < 3; ++ti){
            bf16x8 w = *(const bf16x8*)(wA + ((size_t)(tloc0 + ti) * 1024 + t * 64 + ln * 4 + kq) * 8);
            acc[ti] = __builtin_amdgcn_mfma_f32_16x16x32_bf16(af[t], w, acc[ti], 0, 0, 0);
          }
        }
      } else {
        #pragma unroll
        for (int t = 0; t < 16; ++t){
          #pragma unroll
          for (int ti = 0; ti < 2; ++ti){
            bf16x8 w = *(const bf16x8*)(wA + ((size_t)(tloc0 + ti) * 1024 + t * 64 + ln * 4 + kq) * 8);
            acc[ti] = __builtin_amdgcn_mfma_f32_16x16x32_bf16(af[t], w, acc[ti], 0, 0, 0);
          }
        }
      }
      for (int ti = 0; ti < tcnt; ++ti){
        int col = (t0 + tloc0 + ti) * 16 + ln;
        float bv = bias_big[col];
        #pragma unroll
        for (int r = 0; r < 4; ++r){
          int b = am0 + kq * 4 + r;
          float v = acc[ti][r] + bv;
          if (col < 512){
            st16<FAST>(e16 + (size_t)b * H_DIM + col, (unsigned)f2b(v > 0.f ? v : 0.f));
          } else if (col < 2048){
            st32f<FAST>(gh + (size_t)b * 1536 + (col - 512), v);
          } else {
            out[((size_t)b * T_TOT + T_ENC + s) * O_DIM + (col - 2048)] = v;  // never re-read
          }
        }
      }
    }
    if (s < PRED - 1){
      if constexpr (FAST){
        if (!gbar_fast(sA, abortf, s_ab, rg, sl, (unsigned)(s + 1), tid)) return false;
      } else {
        gbar_slow(sA, rg, sl, (unsigned)(s + 1), tid);
      }
    }
  }
  return true;
}

// epilogue for fast blocks: truthful island convergence; on abort, re-init rows and rerun slow.
static __device__ void fast_epilogue(int rg, int sl, int t0, int nt,
    const short* wA, const short* wB,
    const float* bias_big, const float* b_ih,
    unsigned short* e16, float* gh, float* h, unsigned short* h16, float* out,
    const unsigned short* e0c, const float* ghc, const float* ehid,
    unsigned* abortf, unsigned* s2, unsigned* s3, unsigned* s4, int tid)
{
  gbar_slow(s2, rg, sl, 1u, tid);
  unsigned a = ld_mall(abortf + rg);
  if (a == 0u) return;                       // island healthy: fast results stand

  // re-init this block's slice from pristine state (sc1 so slow loop sees it)
  for (int i = tid; i < 1024; i += 512){
    int r = i >> 4, c = i & 15;
    size_t b = (size_t)(rg * 64 + r);
    int col = sl * 16 + c;
    float hv = ehid[b * H_DIM + col];
    h[b * H_DIM + col] = hv;                                    // plain: block-private
    st16<false>(h16 + b * H_DIM + col, (unsigned)f2b(hv));
    st16<false>(e16 + b * H_DIM + col, (unsigned)e0c[b * H_DIM + col]);
  }
  for (int i = tid; i < 3072; i += 512){
    int r = i / 48, c = i - r * 48;
    size_t b = (size_t)(rg * 64 + r);
    int col = sl * 48 + c;
    st32f<false>(gh + b * 1536 + col, ghc[b * 1536 + col]);
  }
  gbar_slow(s2, rg, sl, 2u, tid);
  run_loop<false>(rg, sl, t0, nt, wA, wB, bias_big, b_ih, e16, gh, h, h16, out,
                  s3, s4, nullptr, nullptr, tid);
}

// sync layout (unsigneds): [0,256) regs | [256,264) cnt | [272,280) abortf |
// [512,1024) fastB | [1024,1536) fastA | [1536,2048) s2 | [2048,2560) s3 | [2560,3072) s4
__global__ __launch_bounds__(512, 1)
void k_persist(const unsigned short* __restrict__ Wbig,
               const unsigned short* __restrict__ wih16,
               const float* __restrict__ bias_big,
               const float* __restrict__ b_ih,
               unsigned short* __restrict__ e16,
               float* __restrict__ gh,
               float* __restrict__ h,
               unsigned short* __restrict__ h16,
               float* __restrict__ out,
               const unsigned short* __restrict__ e0c,
               const float* __restrict__ ghc,
               const float* __restrict__ ehid,
               unsigned* __restrict__ sync)
{
  __shared__ short lds_s[65536];   // 128 KiB: [0,40960) A (<=5 tiles x 16KB), [40960,65536) B (48KB)
  __shared__ unsigned s_xcd, s_rank, s_mode, s_ab;
  unsigned* regs   = sync;
  unsigned* cnt    = sync + 256;
  unsigned* abortf = sync + 272;
  unsigned* fastB  = sync + 512;
  unsigned* fastA  = sync + 1024;
  unsigned* s2     = sync + 1536;
  unsigned* s3     = sync + 2048;
  unsigned* s4     = sync + 2560;
  const int g = blockIdx.x, tid = threadIdx.x;

  // ---- self-organize: rank within my physical XCD ----
  if (tid == 0){
    unsigned x;
    asm volatile("s_getreg_b32 %0, hwreg(HW_REG_XCC_ID)" : "=s"(x));
    x &= 7u;
    unsigned r = __hip_atomic_fetch_add(&cnt[x], 1u, __ATOMIC_RELAXED, __HIP_MEMORY_SCOPE_AGENT);
    s_xcd = x; s_rank = r;
    asm volatile("global_store_dword %0, %1, off sc0 sc1" :: "v"(regs + g), "v"(1u) : "memory");
  }
  __syncthreads();
  // one-time global registration barrier (sc1 flat poll — truthful)
  if (tid < 64){
    const unsigned* p = regs + tid * 4;
    for (;;){
      u32x4 v;
      asm volatile("global_load_dwordx4 %0, %1, off sc0 sc1\n\ts_waitcnt vmcnt(0)" : "=v"(v) : "v"(p) : "memory");
      if (__all((int)((v[0] >= 1u) & (v[1] >= 1u) & (v[2] >= 1u) & (v[3] >= 1u)))) break;
      __builtin_amdgcn_s_sleep(2);
    }
  }
  __syncthreads();
  if (tid == 0){
    unsigned ok = 1u;
    for (int i = 0; i < 8; ++i){
      unsigned c = ld_mall(cnt + i);
      ok &= (c == 32u) ? 1u : 0u;
    }
    s_mode = ok;
  }
  __syncthreads();
  const bool fast = (s_mode != 0u);
  const int rg = fast ? (int)s_xcd  : (g >> 5);   // row-group: rows rg*64 .. +63
  const int sl = fast ? (int)s_rank : (g & 31);   // slice 0..31 within group
  const int t0 = (sl < 4) ? sl * 5 : 20 + (sl - 4) * 4;   // 132 col-tiles over 32 slices
  const int nt = (sl < 4) ? 5 : 4;

  short* wA = lds_s;            // A-slice: nt tiles x 16 cols, k-major 16B granules
  short* wB = lds_s + 40960;    // B-slice: 48 gate-cols (R/Z/N x 16) of w_ih

  for (int q = tid; q < nt * 1024; q += 512){
    int kk = q & 63, c = (q >> 6) & 15, tt = q >> 10;
    bf16x8 v = *(const bf16x8*)(Wbig + (size_t)((t0 + tt) * 16 + c) * H_DIM + kk * 8);
    *(bf16x8*)(wA + ((size_t)tt * 1024 + (kk >> 2) * 64 + c * 4 + (kk & 3)) * 8) = v;
  }
  for (int q = tid; q < 3072; q += 512){
    int kk = q & 63, c = q >> 6;
    int row = ((c >> 4) << 9) + sl * 16 + (c & 15);
    bf16x8 v = *(const bf16x8*)(wih16 + (size_t)row * H_DIM + kk * 8);
    *(bf16x8*)(wB + ((size_t)(kk >> 2) * 192 + c * 4 + (kk & 3)) * 8) = v;
  }
  __syncthreads();

  if (fast){
    (void)run_loop<true>(rg, sl, t0, nt, wA, wB, bias_big, b_ih, e16, gh, h, h16, out,
                         fastB, fastA, abortf, &s_ab, tid);
    fast_epilogue(rg, sl, t0, nt, wA, wB, bias_big, b_ih, e16, gh, h, h16, out,
                  e0c, ghc, ehid, abortf, s2, s3, s4, tid);
  } else {
    run_loop<false>(rg, sl, t0, nt, wA, wB, bias_big, b_ih, e16, gh, h, h16, out,
                    s3, s4, nullptr, nullptr, tid);
  }
}

extern "C" void kernel_launch(void* const* d_in, const int* in_sizes, int n_in,
                              void* d_out, int out_size, void* d_ws, size_t ws_size,
                              hipStream_t stream)
{
  const float* enc   = (const float*)d_in[0];
  const float* ehid  = (const float*)d_in[1];
  const float* embW  = (const float*)d_in[2];
  const float* emb_b = (const float*)d_in[3];
  const float* w_ih  = (const float*)d_in[4];
  const float* w_hh  = (const float*)d_in[5];
  const float* b_ih  = (const float*)d_in[6];
  const float* b_hh  = (const float*)d_in[7];
  const float* out_W = (const float*)d_in[8];
  const float* out_b = (const float*)d_in[9];
  const float* reg_W = (const float*)d_in[10];
  const float* reg_b = (const float*)d_in[11];
  float* out = (float*)d_out;

  char* ws = (char*)d_ws;
  size_t off = 0;
  auto alloc = [&](size_t bytes)->char*{
    char* p = ws + off; off += (bytes + 255) & ~(size_t)255; return p;
  };
  unsigned short* Wbig    = (unsigned short*)alloc((size_t)2112 * 512 * 2);
  unsigned short* wih16   = (unsigned short*)alloc((size_t)1536 * 512 * 2);
  unsigned short* embW16  = (unsigned short*)alloc((size_t)512 * 256 * 2);
  unsigned short* regW16  = (unsigned short*)alloc((size_t)64 * 256 * 2);
  unsigned short* outWT16 = (unsigned short*)alloc((size_t)512 * 256 * 2);
  float*          bias_big= (float*)alloc((size_t)2112 * 4);
  unsigned short* e16     = (unsigned short*)alloc((size_t)512 * 512 * 2);
  float*          gh      = (float*)alloc((size_t)512 * 1536 * 4);
  float*          h       = (float*)alloc((size_t)512 * 512 * 4);
  unsigned short* h16     = (unsigned short*)alloc((size_t)512 * 512 * 2);
  unsigned short* x016    = (unsigned short*)alloc((size_t)512 * 256 * 2);
  unsigned short* e0c     = (unsigned short*)alloc((size_t)512 * 512 * 2);
  float*          ghc     = (float*)alloc((size_t)512 * 1536 * 4);
  unsigned*       sync    = (unsigned*)alloc(16384);

  hipMemsetAsync(sync, 0, 16384, stream);

  // ---- precompute (runs every call; ws is re-poisoned) ----
  k_cast<<<(1536 * 512) / 256, 256, 0, stream>>>(w_ih, wih16, 1536 * 512);
  k_cast<<<(1536 * 512) / 256, 256, 0, stream>>>(w_hh, Wbig + (size_t)512 * 512, 1536 * 512);
  k_cast<<<(512 * 256) / 256, 256, 0, stream>>>(embW, embW16, 512 * 256);
  k_cast<<<(64 * 256) / 256, 256, 0, stream>>>(reg_W, regW16, 64 * 256);
  k_transpose_cast<<<512, 256, 0, stream>>>(out_W, outWT16);
  k_bias<<<9, 256, 0, stream>>>(embW, emb_b, out_b, b_hh, reg_W, reg_b, bias_big);
  k_init_h<<<(512 * 512) / 256, 256, 0, stream>>>(ehid, h, h16);
  k_x0<<<(512 * 256) / 256, 256, 0, stream>>>(enc, x016);

  // W_comb = emb_W @ out_W  -> Wbig rows [0,512)
  k_gemm<<<dim3(8, 8), 256, 0, stream>>>(embW, 1, outWT16, nullptr, Wbig, 1, 512, 512, 256, 512);
  // W_or = reg_W @ out_W  -> Wbig rows [2048,2112)
  k_gemm<<<dim3(8, 1), 256, 0, stream>>>(reg_W, 1, outWT16, nullptr, Wbig + (size_t)2048 * 512, 1, 64, 512, 256, 512);
  // e0 = relu(x0 @ emb_W^T + emb_b)
  k_gemm<<<dim3(8, 8), 256, 0, stream>>>(x016, 0, embW16, emb_b, e16, 2, 512, 512, 256, 512);
  // gh0 = h0 @ w_hh^T + b_hh
  k_gemm<<<dim3(24, 8), 256, 0, stream>>>(h16, 0, Wbig + (size_t)512 * 512, b_hh, gh, 0, 512, 1536, 512, 1536);
  // encoder projection: out[:, 0:140, :] = enc @ reg_W^T + reg_b
  k_gemm<<<dim3(1, 1120), 256, 0, stream>>>(enc, 1, regW16, reg_b, out, 3, 71680, 64, 256, 0);
  // pristine copies for island restart
  k_dup<<<1024, 256, 0, stream>>>(e16, e0c, gh, ghc);

  // ---- 140 GRU steps: XCD-local islands, watchdogged; falls back to sc1 if mapping unhealthy ----
  k_persist<<<dim3(NBLK), dim3(512), 0, stream>>>(Wbig, wih16, bias_big, b_ih,
                                                  e16, gh, h, h16, out, e0c, ghc, ehid, sync);
}

// Round 7
// 2869.830 us; speedup vs baseline: 2.0318x; 1.2853x over previous
//
#include <hip/hip_runtime.h>

#define B_SZ 512
#define T_ENC 140
#define E_DIM 256
#define H_DIM 512
#define O_DIM 64
#define PRED 140
#define T_TOT 280
#define NBLK 256
#define HBUF 262144   // shorts per h16 buffer (8 islands * 32768)

typedef short bf16x8 __attribute__((ext_vector_type(8)));
typedef float f32x4 __attribute__((ext_vector_type(4)));
typedef unsigned u32x4 __attribute__((ext_vector_type(4)));

static __device__ __forceinline__ unsigned short f2b(float x){
  union { float f; unsigned u; } v; v.f = x;
  unsigned r = v.u + 0x7fffu + ((v.u >> 16) & 1u);
  return (unsigned short)(r >> 16);
}
static __device__ __forceinline__ float sigmoidf_(float x){
  return 1.0f / (1.0f + __expf(-x));
}
static __device__ __forceinline__ float tanhf_(float x){
  float e2 = __expf(-2.0f * fabsf(x));
  float t = (1.0f - e2) / (1.0f + e2);
  return x < 0.0f ? -t : t;
}

// invalidate this CU's vector L1. Makes subsequent loads read the local L2.
static __device__ __forceinline__ void binv(){ asm volatile("buffer_inv" ::: "memory"); }

// transports: FAST = same-XCD local L2 (plain stores, binv+sc0 loads); SLOW = MALL (sc0 sc1)
template<bool FAST>
static __device__ __forceinline__ bf16x8 ldx4a(const unsigned short* p){
  f32x4 r;
  if constexpr (FAST) asm volatile("global_load_dwordx4 %0, %1, off sc0" : "=v"(r) : "v"(p));
  else                asm volatile("global_load_dwordx4 %0, %1, off sc0 sc1" : "=v"(r) : "v"(p));
  union { f32x4 f; bf16x8 b; } u; u.f = r; return u.b;
}
template<bool FAST>
static __device__ __forceinline__ void st16(unsigned short* p, unsigned v){
  if constexpr (FAST) asm volatile("global_store_short %0, %1, off" :: "v"(p), "v"(v) : "memory");
  else                asm volatile("global_store_short %0, %1, off sc0 sc1" :: "v"(p), "v"(v) : "memory");
}
static __device__ __forceinline__ void wait_vm0(){
  asm volatile("s_waitcnt vmcnt(0)" ::: "memory");
  __builtin_amdgcn_sched_barrier(0);
}
static __device__ __forceinline__ unsigned ld_mall(const unsigned* p){
  unsigned r;
  asm volatile("global_load_dword %0, %1, off sc0 sc1\n\ts_waitcnt vmcnt(0)" : "=v"(r) : "v"(p) : "memory");
  return r;
}
static __device__ __forceinline__ void st_mall(unsigned* p, unsigned v){
  asm volatile("global_store_dword %0, %1, off sc0 sc1\n\ts_waitcnt vmcnt(0)" :: "v"(p), "v"(v) : "memory");
}

__global__ void k_cast(const float* __restrict__ src, unsigned short* __restrict__ dst, int n){
  int i = blockIdx.x * 256 + threadIdx.x;
  if (i < n) dst[i] = f2b(src[i]);
}

__global__ void k_transpose_cast(const float* __restrict__ src, unsigned short* __restrict__ dst){
  int i = blockIdx.x * 256 + threadIdx.x;   // over H*E = 131072
  int j = i >> 8;
  int k = i & 255;
  dst[i] = f2b(src[k * H_DIM + j]);
}

// h16 buffer 1 (parity s=-1) in PACKED layout [rg][sl][row][16]
__global__ void k_init_h(const float* __restrict__ eh, unsigned short* __restrict__ h16){
  int i = blockIdx.x * 256 + threadIdx.x;   // B*H
  int b = i >> 9, col = i & 511;
  h16[HBUF + (((size_t)(b >> 6) * 32 + (col >> 4)) * 64 + (b & 63)) * 16 + (col & 15)] = f2b(eh[i]);
}

__global__ void k_x0(const float* __restrict__ enc, unsigned short* __restrict__ x016){
  int i = blockIdx.x * 256 + threadIdx.x;   // B*E
  int b = i >> 8; int k = i & 255;
  x016[i] = f2b(enc[((size_t)b * T_ENC + (T_ENC - 1)) * E_DIM + k]);
}

__global__ void k_dup(const unsigned short* __restrict__ e16, unsigned short* __restrict__ e0c){
  int i = blockIdx.x * 256 + threadIdx.x;   // 262144
  e0c[i] = e16[i];
}

// bias_big = [emb_b + emb_W@out_b (512) | b_hh (1536) | reg_b + reg_W@out_b (64)]
__global__ void k_bias(const float* __restrict__ embW, const float* __restrict__ emb_b,
                       const float* __restrict__ out_b, const float* __restrict__ b_hh,
                       const float* __restrict__ regW, const float* __restrict__ reg_b,
                       float* __restrict__ bias_big){
  int i = blockIdx.x * 256 + threadIdx.x;
  if (i < 512){
    float s = emb_b[i];
    for (int k = 0; k < 256; k++) s += embW[i * 256 + k] * out_b[k];
    bias_big[i] = s;
  } else if (i < 2048){
    bias_big[i] = b_hh[i - 512];
  } else if (i < 2112){
    int o = i - 2048;
    float s = reg_b[o];
    for (int k = 0; k < 256; k++) s += regW[o * 256 + k] * out_b[k];
    bias_big[i] = s;
  }
}

// Generic C = A @ W^T (+bias). modes: 0 f32; 1 bf16; 2 relu bf16; 3 enc remap; 4 relu bf16 PACKED
__global__ __launch_bounds__(256)
void k_gemm(const void* __restrict__ Aptr, int a_is_f32,
            const unsigned short* __restrict__ W,
            const float* __restrict__ bias,
            void* __restrict__ Cptr, int mode,
            int M, int N, int K, int ldc)
{
  const int lane = threadIdx.x & 63;
  const int wave = threadIdx.x >> 6;
  const int ln = lane & 15;
  const int kq = lane >> 4;
  const int m0 = blockIdx.y * 64 + wave * 16;
  const int n0 = blockIdx.x * 64;

  f32x4 acc[4] = {};
  const int arow = m0 + ln;
  const unsigned short* wp = W + (size_t)(n0 + ln) * K + kq * 8;
  const int nk = K >> 5;

  if (a_is_f32){
    const float* ap = (const float*)Aptr + (size_t)arow * K + kq * 8;
    for (int t = 0; t < nk; ++t){
      f32x4 u0 = *(const f32x4*)(ap);
      f32x4 u1 = *(const f32x4*)(ap + 4);
      bf16x8 af;
      af[0] = (short)f2b(u0[0]); af[1] = (short)f2b(u0[1]);
      af[2] = (short)f2b(u0[2]); af[3] = (short)f2b(u0[3]);
      af[4] = (short)f2b(u1[0]); af[5] = (short)f2b(u1[1]);
      af[6] = (short)f2b(u1[2]); af[7] = (short)f2b(u1[3]);
      #pragma unroll
      for (int j = 0; j < 4; j++){
        bf16x8 wf = *(const bf16x8*)(wp + (size_t)(16 * j) * K);
        acc[j] = __builtin_amdgcn_mfma_f32_16x16x32_bf16(af, wf, acc[j], 0, 0, 0);
      }
      ap += 32; wp += 32;
    }
  } else {
    const unsigned short* ap = (const unsigned short*)Aptr + (size_t)arow * K + kq * 8;
    for (int t = 0; t < nk; ++t){
      bf16x8 af = *(const bf16x8*)ap;
      #pragma unroll
      for (int j = 0; j < 4; j++){
        bf16x8 wf = *(const bf16x8*)(wp + (size_t)(16 * j) * K);
        acc[j] = __builtin_amdgcn_mfma_f32_16x16x32_bf16(af, wf, acc[j], 0, 0, 0);
      }
      ap += 32; wp += 32;
    }
  }

  #pragma unroll
  for (int j = 0; j < 4; j++){
    int col = n0 + 16 * j + ln;
    float bv = bias ? bias[col] : 0.0f;
    #pragma unroll
    for (int r = 0; r < 4; r++){
      int orow = m0 + kq * 4 + r;
      float v = acc[j][r] + bv;
      if (mode == 0){
        ((float*)Cptr)[(size_t)orow * ldc + col] = v;
      } else if (mode == 1){
        ((unsigned short*)Cptr)[(size_t)orow * ldc + col] = f2b(v);
      } else if (mode == 2){
        ((unsigned short*)Cptr)[(size_t)orow * ldc + col] = f2b(v > 0.f ? v : 0.f);
      } else if (mode == 3){
        int bb = orow / T_ENC;
        int tt = orow - bb * T_ENC;
        ((float*)Cptr)[((size_t)bb * T_TOT + tt) * O_DIM + col] = v;
      } else {
        ((unsigned short*)Cptr)[(((size_t)(orow >> 6) * 32 + (col >> 4)) * 64 + (orow & 63)) * 16 + (col & 15)]
          = f2b(v > 0.f ? v : 0.f);
      }
    }
  }
}

// ---------------- persistent GRU: XCD islands, gh/h memory-free, packed tiles ----------------

static __device__ void gbar_slow(unsigned* slots, int rg, int sl, unsigned gen, int tid){
  asm volatile("s_waitcnt vmcnt(0)" ::: "memory");
  __syncthreads();
  if (tid < 64){
    unsigned* base = slots + rg * 64;
    if (tid == 0){
      asm volatile("global_store_dword %0, %1, off sc0 sc1" :: "v"(base + sl), "v"(gen) : "memory");
    }
    const unsigned* p = base + (tid & 31);
    for (;;){
      unsigned v;
      asm volatile("global_load_dword %0, %1, off sc0 sc1\n\ts_waitcnt vmcnt(0)" : "=v"(v) : "v"(p) : "memory");
      if (__all((int)(v >= gen))) break;
      __builtin_amdgcn_s_sleep(8);
    }
  }
  __syncthreads();
}

static __device__ __forceinline__ bool gbar_fast(unsigned* slots, unsigned* abortf,
                                                 volatile unsigned* s_ab, int rg, int sl,
                                                 unsigned gen, int tid){
  asm volatile("s_waitcnt vmcnt(0)" ::: "memory");
  __syncthreads();
  if (tid < 64){
    unsigned* base = slots + rg * 64;
    if (tid == 0){
      asm volatile("global_store_dword %0, %1, off sc0" :: "v"(base + sl), "v"(gen) : "memory");
    }
    const unsigned* p = base + (tid & 31);
    unsigned it = 0, ab = 0;
    for (;;){
      binv();
      unsigned v;
      asm volatile("global_load_dword %0, %1, off sc0\n\ts_waitcnt vmcnt(0)" : "=v"(v) : "v"(p) : "memory");
      if (__all((int)(v >= gen))) break;
      if ((++it & 2047u) == 0u){
        unsigned a = ld_mall(abortf + rg);
        if (a != 0u || it >= 16384u){
          if (a == 0u && tid == 0) st_mall(abortf + rg, 1u);
          ab = 1u; break;
        }
      }
    }
    if (tid == 0) *s_ab = ab;
  }
  __syncthreads();
  return *s_ab == 0u;
}

// unified step loop; FAST aborts return false. h in VGPRs; gh via LDS handoff; packed tiles.
template<bool FAST>
static __device__ bool run_loop(int rg, int sl,
    const short* wA_e, const short* wA_y, const short* wB_ih, const short* wB_hh,
    float* ghbuf,
    const float* __restrict__ bias_big, const float* __restrict__ b_ih,
    unsigned short* __restrict__ e16,
    unsigned short* __restrict__ h16,
    float* __restrict__ out,
    const float* __restrict__ ehid,
    unsigned* sB, unsigned* sA, unsigned* abortf, volatile unsigned* s_ab, int tid)
{
  const int wv = tid >> 6, lane = tid & 63, ln = lane & 15, kq = lane >> 4;
  const int jcol = sl * 16 + ln;
  // waves 0-3: gi biases; waves 4-7: gh biases (= bias_big[512..2048) = b_hh)
  const float b0 = (wv < 4) ? b_ih[jcol] : bias_big[512 + jcol];
  const float b1 = (wv < 4) ? b_ih[512 + jcol] : bias_big[1024 + jcol];
  const float b2 = (wv < 4) ? b_ih[1024 + jcol] : bias_big[1536 + jcol];
  const float bvE = bias_big[sl * 16 + ln];
  const float bvY = (sl < 4) ? bias_big[2048 + sl * 16 + ln] : 0.f;

  unsigned short* const eb = e16 + (size_t)rg * 32768;      // island e16 base (packed)
  unsigned short* const hb0 = h16 + (size_t)rg * 32768;     // h16 parity-0 island base
  unsigned short* const hb1 = h16 + HBUF + (size_t)rg * 32768;

  // h state in registers (waves 0-3 only)
  float hreg[4];
  if (wv < 4){
    #pragma unroll
    for (int r = 0; r < 4; ++r)
      hreg[r] = ehid[((size_t)rg * 64 + wv * 16 + kq * 4 + r) * H_DIM + jcol];
  }

  const int apoff = (kq >> 1) * 1024 + (kq & 1) * 8;        // packed-tile lane offset

  for (int s = 0; s < PRED; ++s){
    unsigned short* const hw = (s & 1) ? hb1 : hb0;         // h(s)   written by B
    unsigned short* const hr = (s & 1) ? hb0 : hb1;         // h(s-1) read by gh-GEMM

    // ---- phase B: waves 0-3 gi = e@w_ih ; waves 4-7 gh = h(s-1)@w_hh -> LDS ; gating ----
    {
      if constexpr (FAST) binv();
      const unsigned short* ap = (wv < 4)
        ? (eb + apoff + ((wv       * 16 + ln) * 16))
        : (hr + apoff + (((wv - 4) * 16 + ln) * 16));
      bf16x8 af[16];
      #pragma unroll
      for (int t = 0; t < 16; ++t) af[t] = ldx4a<FAST>(ap + t * 2048);
      wait_vm0();
      f32x4 aR = {}, aZ = {}, aN = {};
      const short* lb = ((wv < 4) ? wB_ih : wB_hh) + (ln * 4 + kq) * 8;
      #pragma unroll
      for (int t = 0; t < 16; ++t){
        aR = __builtin_amdgcn_mfma_f32_16x16x32_bf16(af[t], *(const bf16x8*)(lb + (t * 192      ) * 8), aR, 0, 0, 0);
        aZ = __builtin_amdgcn_mfma_f32_16x16x32_bf16(af[t], *(const bf16x8*)(lb + (t * 192 +  64) * 8), aZ, 0, 0, 0);
        aN = __builtin_amdgcn_mfma_f32_16x16x32_bf16(af[t], *(const bf16x8*)(lb + (t * 192 + 128) * 8), aN, 0, 0, 0);
      }
      if (wv >= 4){
        #pragma unroll
        for (int r = 0; r < 4; ++r){
          int row = (wv - 4) * 16 + kq * 4 + r;
          ghbuf[row * 48 + ln]      = aR[r] + b0;
          ghbuf[row * 48 + 16 + ln] = aZ[r] + b1;
          ghbuf[row * 48 + 32 + ln] = aN[r] + b2;
        }
      }
      __syncthreads();
      if (wv < 4){
        #pragma unroll
        for (int r = 0; r < 4; ++r){
          int row = wv * 16 + kq * 4 + r;
          float gR = ghbuf[row * 48 + ln];
          float gZ = ghbuf[row * 48 + 16 + ln];
          float gN = ghbuf[row * 48 + 32 + ln];
          float rr = sigmoidf_(aR[r] + b0 + gR);
          float z  = sigmoidf_(aZ[r] + b1 + gZ);
          float nn = tanhf_(aN[r] + b2 + rr * gN);
          float hv = (1.f - z) * nn + z * hreg[r];
          hreg[r] = hv;
          st16<FAST>(hw + (size_t)sl * 1024 + row * 16 + ln, (unsigned)f2b(hv));
        }
      }
    }
    if constexpr (FAST){
      if (!gbar_fast(sB, abortf, s_ab, rg, sl, (unsigned)(s + 1), tid)) return false;
    } else {
      gbar_slow(sB, rg, sl, (unsigned)(s + 1), tid);
    }

    // ---- phase A: waves 0-3 e-tile sl ; waves 4-7 y-tile (sl<4) ----
    if (wv < 4 || sl < 4){
      if constexpr (FAST) binv();
      const unsigned short* ap = hw + apoff + (((wv & 3) * 16 + ln) * 16);
      bf16x8 af[16];
      #pragma unroll
      for (int t = 0; t < 16; ++t) af[t] = ldx4a<FAST>(ap + t * 2048);
      wait_vm0();
      const short* wf = ((wv < 4) ? wA_e : wA_y) + (ln * 4 + kq) * 8;
      f32x4 acc = {};
      #pragma unroll
      for (int t = 0; t < 16; ++t)
        acc = __builtin_amdgcn_mfma_f32_16x16x32_bf16(af[t], *(const bf16x8*)(wf + (t * 64) * 8), acc, 0, 0, 0);
      if (wv < 4){
        #pragma unroll
        for (int r = 0; r < 4; ++r){
          int row = wv * 16 + kq * 4 + r;
          float v = acc[r] + bvE;
          st16<FAST>(eb + (size_t)sl * 1024 + row * 16 + ln, (unsigned)f2b(v > 0.f ? v : 0.f));
        }
      } else {
        #pragma unroll
        for (int r = 0; r < 4; ++r){
          size_t b = (size_t)rg * 64 + (wv - 4) * 16 + kq * 4 + r;
          out[(b * T_TOT + T_ENC + s) * O_DIM + sl * 16 + ln] = acc[r] + bvY;   // never re-read
        }
      }
    }
    if (s < PRED - 1){
      if constexpr (FAST){
        if (!gbar_fast(sA, abortf, s_ab, rg, sl, (unsigned)(s + 1), tid)) return false;
      } else {
        gbar_slow(sA, rg, sl, (unsigned)(s + 1), tid);
      }
    }
  }
  return true;
}

static __device__ void fast_epilogue(int rg, int sl,
    const short* wA_e, const short* wA_y, const short* wB_ih, const short* wB_hh,
    float* ghbuf,
    const float* bias_big, const float* b_ih,
    unsigned short* e16, unsigned short* h16, float* out,
    const unsigned short* e0c, const float* ehid,
    unsigned* abortf, unsigned* s2, unsigned* s3, unsigned* s4, int tid)
{
  gbar_slow(s2, rg, sl, 1u, tid);
  unsigned a = ld_mall(abortf + rg);
  if (a == 0u) return;                       // island healthy: fast results stand

  // restore this block's slices from pristine state (sc1)
  const size_t base = (size_t)rg * 32768 + (size_t)sl * 1024;
  for (int i = tid; i < 1024; i += 512){
    int row = i >> 4, c = i & 15;
    st16<false>(e16 + base + row * 16 + c, (unsigned)e0c[base + row * 16 + c]);
    float v = ehid[((size_t)rg * 64 + row) * H_DIM + sl * 16 + c];
    st16<false>(h16 + HBUF + base + row * 16 + c, (unsigned)f2b(v));
  }
  gbar_slow(s2, rg, sl, 2u, tid);
  run_loop<false>(rg, sl, wA_e, wA_y, wB_ih, wB_hh, ghbuf, bias_big, b_ih,
                  e16, h16, out, ehid, s3, s4, nullptr, nullptr, tid);
}

// sync layout (unsigneds): [0,256) regs | [256,264) cnt | [272,280) abortf |
// [512,1024) fastB | [1024,1536) fastA | [1536,2048) s2 | [2048,2560) s3 | [2560,3072) s4
__global__ __launch_bounds__(512, 1)
void k_persist(const unsigned short* __restrict__ Wbig,
               const unsigned short* __restrict__ wih16,
               const float* __restrict__ bias_big,
               const float* __restrict__ b_ih,
               unsigned short* __restrict__ e16,
               unsigned short* __restrict__ h16,
               float* __restrict__ out,
               const unsigned short* __restrict__ e0c,
               const float* __restrict__ ehid,
               unsigned* __restrict__ sync)
{
  __shared__ short lds_s[65536];   // 128 KiB: [0,8192) wA_e | [8192,16384) wA_y | [16384,40960) wB_ih | [40960,65536) wB_hh
  __shared__ float ghbuf[3072];    // 12 KiB gh handoff (64 rows x 3 gates x 16)
  __shared__ unsigned s_xcd, s_rank, s_mode, s_ab;
  unsigned* regs   = sync;
  unsigned* cnt    = sync + 256;
  unsigned* abortf = sync + 272;
  unsigned* fastB  = sync + 512;
  unsigned* fastA  = sync + 1024;
  unsigned* s2     = sync + 1536;
  unsigned* s3     = sync + 2048;
  unsigned* s4     = sync + 2560;
  const int g = blockIdx.x, tid = threadIdx.x;

  if (tid == 0){
    unsigned x;
    asm volatile("s_getreg_b32 %0, hwreg(HW_REG_XCC_ID)" : "=s"(x));
    x &= 7u;
    unsigned r = __hip_atomic_fetch_add(&cnt[x], 1u, __ATOMIC_RELAXED, __HIP_MEMORY_SCOPE_AGENT);
    s_xcd = x; s_rank = r;
    asm volatile("global_store_dword %0, %1, off sc0 sc1" :: "v"(regs + g), "v"(1u) : "memory");
  }
  __syncthreads();
  if (tid < 64){
    const unsigned* p = regs + tid * 4;
    for (;;){
      u32x4 v;
      asm volatile("global_load_dwordx4 %0, %1, off sc0 sc1\n\ts_waitcnt vmcnt(0)" : "=v"(v) : "v"(p) : "memory");
      if (__all((int)((v[0] >= 1u) & (v[1] >= 1u) & (v[2] >= 1u) & (v[3] >= 1u)))) break;
      __builtin_amdgcn_s_sleep(2);
    }
  }
  __syncthreads();
  if (tid == 0){
    unsigned ok = 1u;
    for (int i = 0; i < 8; ++i){
      unsigned c = ld_mall(cnt + i);
      ok &= (c == 32u) ? 1u : 0u;
    }
    s_mode = ok;
  }
  __syncthreads();
  const bool fast = (s_mode != 0u);
  const int rg = fast ? (int)s_xcd  : (g >> 5);
  const int sl = fast ? (int)s_rank : (g & 31);

  short* wA_e  = lds_s;
  short* wA_y  = lds_s + 8192;
  short* wB_ih = lds_s + 16384;
  short* wB_hh = lds_s + 40960;

  // stage weights (k-major 16B granules): A-e = W_comb rows sl*16..+16; A-y = Wbig rows 2048+sl*16 (sl<4)
  for (int q = tid; q < 1024; q += 512){
    int kk = q & 63, c = q >> 6;
    bf16x8 v = *(const bf16x8*)(Wbig + (size_t)(sl * 16 + c) * H_DIM + kk * 8);
    *(bf16x8*)(wA_e + ((kk >> 2) * 64 + c * 4 + (kk & 3)) * 8) = v;
  }
  if (sl < 4){
    for (int q = tid; q < 1024; q += 512){
      int kk = q & 63, c = q >> 6;
      bf16x8 v = *(const bf16x8*)(Wbig + (size_t)(2048 + sl * 16 + c) * H_DIM + kk * 8);
      *(bf16x8*)(wA_y + ((kk >> 2) * 64 + c * 4 + (kk & 3)) * 8) = v;
    }
  }
  // B: 48 gate-cols of w_ih and of w_hh (w_hh lives at Wbig rows 512..2048)
  for (int q = tid; q < 3072; q += 512){
    int kk = q & 63, c = q >> 6;
    int phys = ((kk >> 2) * 192 + c * 4 + (kk & 3)) * 8;
    int row = ((c >> 4) << 9) + sl * 16 + (c & 15);
    *(bf16x8*)(wB_ih + phys) = *(const bf16x8*)(wih16 + (size_t)row * H_DIM + kk * 8);
    *(bf16x8*)(wB_hh + phys) = *(const bf16x8*)(Wbig + (size_t)(512 + row) * H_DIM + kk * 8);
  }
  __syncthreads();

  if (fast){
    (void)run_loop<true>(rg, sl, wA_e, wA_y, wB_ih, wB_hh, ghbuf, bias_big, b_ih,
                         e16, h16, out, ehid, fastB, fastA, abortf, &s_ab, tid);
    fast_epilogue(rg, sl, wA_e, wA_y, wB_ih, wB_hh, ghbuf, bias_big, b_ih,
                  e16, h16, out, e0c, ehid, abortf, s2, s3, s4, tid);
  } else {
    run_loop<false>(rg, sl, wA_e, wA_y, wB_ih, wB_hh, ghbuf, bias_big, b_ih,
                    e16, h16, out, ehid, s3, s4, nullptr, nullptr, tid);
  }
}

extern "C" void kernel_launch(void* const* d_in, const int* in_sizes, int n_in,
                              void* d_out, int out_size, void* d_ws, size_t ws_size,
                              hipStream_t stream)
{
  const float* enc   = (const float*)d_in[0];
  const float* ehid  = (const float*)d_in[1];
  const float* embW  = (const float*)d_in[2];
  const float* emb_b = (const float*)d_in[3];
  const float* w_ih  = (const float*)d_in[4];
  const float* w_hh  = (const float*)d_in[5];
  const float* b_ih  = (const float*)d_in[6];
  const float* b_hh  = (const float*)d_in[7];
  const float* out_W = (const float*)d_in[8];
  const float* out_b = (const float*)d_in[9];
  const float* reg_W = (const float*)d_in[10];
  const float* reg_b = (const float*)d_in[11];
  float* out = (float*)d_out;

  char* ws = (char*)d_ws;
  size_t off = 0;
  auto alloc = [&](size_t bytes)->char*{
    char* p = ws + off; off += (bytes + 255) & ~(size_t)255; return p;
  };
  unsigned short* Wbig    = (unsigned short*)alloc((size_t)2112 * 512 * 2);
  unsigned short* wih16   = (unsigned short*)alloc((size_t)1536 * 512 * 2);
  unsigned short* embW16  = (unsigned short*)alloc((size_t)512 * 256 * 2);
  unsigned short* regW16  = (unsigned short*)alloc((size_t)64 * 256 * 2);
  unsigned short* outWT16 = (unsigned short*)alloc((size_t)512 * 256 * 2);
  float*          bias_big= (float*)alloc((size_t)2112 * 4);
  unsigned short* e16     = (unsigned short*)alloc((size_t)262144 * 2);       // packed
  unsigned short* h16     = (unsigned short*)alloc((size_t)2 * HBUF * 2);     // 2 parity buffers, packed
  unsigned short* x016    = (unsigned short*)alloc((size_t)512 * 256 * 2);
  unsigned short* e0c     = (unsigned short*)alloc((size_t)262144 * 2);
  unsigned*       sync    = (unsigned*)alloc(16384);

  hipMemsetAsync(sync, 0, 16384, stream);

  // ---- precompute ----
  k_cast<<<(1536 * 512) / 256, 256, 0, stream>>>(w_ih, wih16, 1536 * 512);
  k_cast<<<(1536 * 512) / 256, 256, 0, stream>>>(w_hh, Wbig + (size_t)512 * 512, 1536 * 512);
  k_cast<<<(512 * 256) / 256, 256, 0, stream>>>(embW, embW16, 512 * 256);
  k_cast<<<(64 * 256) / 256, 256, 0, stream>>>(reg_W, regW16, 64 * 256);
  k_transpose_cast<<<512, 256, 0, stream>>>(out_W, outWT16);
  k_bias<<<9, 256, 0, stream>>>(embW, emb_b, out_b, b_hh, reg_W, reg_b, bias_big);
  k_init_h<<<(512 * 512) / 256, 256, 0, stream>>>(ehid, h16);
  k_x0<<<(512 * 256) / 256, 256, 0, stream>>>(enc, x016);

  // W_comb = emb_W @ out_W -> Wbig rows [0,512)
  k_gemm<<<dim3(8, 8), 256, 0, stream>>>(embW, 1, outWT16, nullptr, Wbig, 1, 512, 512, 256, 512);
  // W_or = reg_W @ out_W -> Wbig rows [2048,2112)
  k_gemm<<<dim3(8, 1), 256, 0, stream>>>(reg_W, 1, outWT16, nullptr, Wbig + (size_t)2048 * 512, 1, 64, 512, 256, 512);
  // e0 = relu(x0 @ emb_W^T + emb_b) -> PACKED e16
  k_gemm<<<dim3(8, 8), 256, 0, stream>>>(x016, 0, embW16, emb_b, e16, 4, 512, 512, 256, 512);
  // encoder projection
  k_gemm<<<dim3(1, 1120), 256, 0, stream>>>(enc, 1, regW16, reg_b, out, 3, 71680, 64, 256, 0);
  // pristine e0 copy for island restart
  k_dup<<<1024, 256, 0, stream>>>(e16, e0c);

  // ---- 140 GRU steps: XCD islands; gh and h never touch memory; packed full-line stores ----
  k_persist<<<dim3(NBLK), dim3(512), 0, stream>>>(Wbig, wih16, bias_big, b_ih,
                                                  e16, h16, out, e0c, ehid, sync);
}